// Round 1
// 430.175 us; speedup vs baseline: 1.0164x; 1.0164x over previous
//
#include <hip/hip_runtime.h>

typedef _Float16 half_t;
typedef float v4f __attribute__((ext_vector_type(4)));

#define NSEG 34   // table segments (table has 35 entries)
#define NT   10   // bins

__device__ __forceinline__ half_t lo_h(unsigned u) {
    union { unsigned u; half_t h[2]; } v; v.u = u; return v.h[0];
}
__device__ __forceinline__ half_t hi_h(unsigned u) {
    union { unsigned u; half_t h[2]; } v; v.u = u; return v.h[1];
}

struct Consts {
    float cc[9];      // cut[1..9] (f32)
    float c0f, clf;   // clamp bounds (f32)
    float t0, tl;     // table[0], table[34] raw f32 (boundary overrides)
};

__device__ __forceinline__ float eval_one(float xf, const Consts& C,
                                          const float2* s_bins,
                                          const unsigned* s_pair)
{
    // xc = f16(clip(x, c0, cl)); NaN -> 0. All downstream math on v = f32(xc).
    float xcf = fminf(fmaxf(xf, C.c0f), C.clf);
    half_t xh = (half_t)xcf;
    if (!(xf == xf)) xh = (half_t)0.0f;
    float v = (float)xh;

    // ci = clip(searchsorted(cut, v, 'right'), 1, 10) - 1 = sum_{j=1..9}(v >= cut[j])
    int ci = 0;
#pragma unroll
    for (int j = 0; j < 9; ++j) ci += (v >= C.cc[j]) ? 1 : 0;

    // dval, temp in f32 (f16 - f32 promotes to f32 in the reference);
    // scale is f16-rounded then used in f32.
    float2 b = s_bins[ci];           // {cut[ci], (f32)(f16)mscale[ci]}
    float temp = (v - b.x) * b.y;    // temp >= 0 by construction
    int idx = (int)temp;             // trunc == floor for temp >= 0
    idx = (ci == 9 && idx == 1) ? 0 : idx;
    float dec = temp - (float)idx;   // f32, idx exact

    // tbl = idx (ci==0) else 1+(ci-1)*4+idx  == idx + max(4*ci-3, 0)
    int tbl = idx + max(4 * ci - 3, 0);
    unsigned pr = s_pair[tbl];       // {f16(table[tbl]), f16(table[tbl+1])}
    half_t lh = lo_h(pr);
    half_t rh = hi_h(pr);
    half_t interval = rh - lh;       // f16 sub, as reference
    float y = (float)lh + (float)interval * dec;   // f16 + f16*f32 -> f32

    // boundary overrides use raw f32 table endpoints
    y = (v <= C.c0f) ? C.t0 : y;
    y = (v >= C.clf) ? C.tl : y;

    return fminf(fmaxf(y, -65504.0f), 65504.0f);
}

__device__ __forceinline__ v4f eval4(v4f v, const Consts& C,
                                     const float2* s_bins,
                                     const unsigned* s_pair)
{
    v4f r;
    r.x = eval_one(v.x, C, s_bins, s_pair);
    r.y = eval_one(v.y, C, s_bins, s_pair);
    r.z = eval_one(v.z, C, s_bins, s_pair);
    r.w = eval_one(v.w, C, s_bins, s_pair);
    return r;
}

__global__ __launch_bounds__(256) void gelu_lut_kernel(
    const float* __restrict__ x,
    const float* __restrict__ cutf,    // f32, 11 entries (fp16 promoted by harness)
    const float* __restrict__ table,   // f32, 35 entries
    const float* __restrict__ mscale,  // f32, 10 entries
    float* __restrict__ out,
    int n4, int n)
{
    __shared__ float2   s_bins[NT];    // {cut, (f32)(f16)mscale} per bin
    __shared__ unsigned s_pair[NSEG];  // {f16 left, f16 right} per segment

    const int t = threadIdx.x;
    if (t < NSEG) {
        union { half_t h[2]; unsigned u; } p;
        p.h[0] = (half_t)table[t];
        p.h[1] = (half_t)table[t + 1];
        s_pair[t] = p.u;
    }
    if (t < NT) {
        s_bins[t] = make_float2(cutf[t], (float)(half_t)mscale[t]);
    }

    Consts C;
#pragma unroll
    for (int j = 0; j < 9; ++j) C.cc[j] = cutf[j + 1];
    C.c0f = cutf[0];
    C.clf = cutf[10];
    C.t0  = table[0];
    C.tl  = table[NSEG];
    __syncthreads();

    const v4f* __restrict__ x4 = (const v4f*)x;
    v4f* __restrict__ o4 = (v4f*)out;
    const int stride = gridDim.x * blockDim.x;

    int i = blockIdx.x * blockDim.x + t;

    // Main loop: 2 independent dwordx4 loads in flight per iteration (MLP x2),
    // nontemporal (streaming) hints on both loads and stores.
    for (; i + stride < n4; i += 2 * stride) {
        v4f a = __builtin_nontemporal_load(x4 + i);
        v4f b = __builtin_nontemporal_load(x4 + i + stride);
        v4f ra = eval4(a, C, s_bins, s_pair);
        __builtin_nontemporal_store(ra, o4 + i);
        v4f rb = eval4(b, C, s_bins, s_pair);
        __builtin_nontemporal_store(rb, o4 + i + stride);
    }
    // At most one leftover float4 per thread (pair-loop exit => i+stride >= n4).
    if (i < n4) {
        v4f a = __builtin_nontemporal_load(x4 + i);
        v4f ra = eval4(a, C, s_bins, s_pair);
        __builtin_nontemporal_store(ra, o4 + i);
    }

    // tail (n not divisible by 4) — block 0 only
    const int base = n4 * 4;
    if (blockIdx.x == 0) {
        for (int j = base + t; j < n; j += (int)blockDim.x)
            out[j] = eval_one(x[j], C, s_bins, s_pair);
    }
}

extern "C" void kernel_launch(void* const* d_in, const int* in_sizes, int n_in,
                              void* d_out, int out_size, void* d_ws, size_t ws_size,
                              hipStream_t stream) {
    const float* x      = (const float*)d_in[0];
    const float* cutf   = (const float*)d_in[1];  // fp16 in reference, staged as f32
    const float* table  = (const float*)d_in[2];
    const float* mscale = (const float*)d_in[3];
    float* out          = (float*)d_out;

    const int n  = in_sizes[0];
    const int n4 = n >> 2;

    const int threads = 256;
    int need = (n4 + threads - 1) / threads;
    if (need < 1) need = 1;
    int grid = need < 8192 ? need : 8192;

    gelu_lut_kernel<<<grid, threads, 0, stream>>>(x, cutf, table, mscale, out, n4, n);
}